// Round 9
// baseline (374.789 us; speedup 1.0000x reference)
//
#include <hip/hip_runtime.h>

// Fused 2-layer LSTM (H=50, D=5, T=512, B=4096) + linear head — v7.
// = v5 (372 us, proven) + safe v6 grafts only. R8's v_pk_*_f32 inline asm
// NaN'd (ops absent from the gfx950 verified ISA list) — abandoned.
//   * TICK order: ds_reads first under setprio(1); x(t+1) copy sits in the
//     ds_read latency shadow; MFMA; setprio(0); cell update.
//   * x-copy spread 20 lanes x 4 L0 waves (SIMD-balanced, off L1 waves).
//   * cell math unguarded (pad lanes bounded-harmless); only h-store masked.
// grid=256 (1 block/CU), block=512 (8 waves), NB=16 batches/block.
// Waves 0-3: layer-0 step t; waves 4-7: layer-1 step t-1; ONE barrier/tick.
// 7-trans cell update (5 exp2 + 2 rcp), bias as MFMA C operand, 2x unroll.

#define NB 16
#define BLK 512
#define TT 512
#define LOG2E 1.44269504088896340736f
#define SA 72            // _Float16 per A row (K=64 pad, skewed stride)
#define SXR 264          // floats per batch row of x chunk

typedef _Float16 half8 __attribute__((ext_vector_type(8)));
typedef __attribute__((ext_vector_type(4))) float f32x4;

#define MFMAH(a, b, c) __builtin_amdgcn_mfma_f32_16x16x32_f16((a), (b), (c), 0, 0, 0)

__device__ __forceinline__ float fexp2(float x) { return __builtin_amdgcn_exp2f(x); }
__device__ __forceinline__ float frcp(float x)  { return __builtin_amdgcn_rcpf(x); }

// ---- 7-trans activation + cell + h-write for 4 batch rows ----
// c' = [c(1+eu)(1+ev) + (1-ev)(1+ew)] / [(1+eu)(1+ev)(1+ew)]
// h  = (1-ez)/((1+ey)(1+ez)), ez = exp2(min(-2log2e*c', 80))
#define CELL_UPDATE(ACCX, BUF, WBX)                                         \
    _Pragma("unroll")                                                       \
    for (int r = 0; r < 4; ++r) {                                           \
        float eu = fexp2(ACCX[0][r]);   /* i */                             \
        float ew = fexp2(ACCX[1][r]);   /* f */                             \
        float ev = fexp2(ACCX[2][r]);   /* g (2x scale) */                  \
        float ey = fexp2(ACCX[3][r]);   /* o */                             \
        float pu = 1.f + eu, pw = 1.f + ew, pv = 1.f + ev;                  \
        float P  = pu * pv;                                                 \
        float rD = frcp(P * pw);                                            \
        float N  = cst[r] * P + (2.f - pv) * pw;                            \
        float cn = N * rD;                                                  \
        cst[r] = cn;                                                        \
        float za = fminf(cn * (-2.f * LOG2E), 80.f);                        \
        float ez = fexp2(za);                                               \
        float pz = 1.f + ez, py = 1.f + ey;                                 \
        float rQ = frcp(py * pz);                                           \
        float h  = (2.f - pz) * rQ;                                         \
        if (jv) BUF[WBX][(4 * c + r) * SA + j] = (_Float16)h;               \
    }

// ---- one pipeline tick; RB/WB are literal 0/1 ----
#define TICK(T, RB, WB)                                                     \
    {                                                                       \
        if (grp == 0) {                                                     \
            if ((T) < TT) {                                                 \
                __builtin_amdgcn_s_setprio(1);                              \
                half8 a0 = *(const half8*)&sA0[RB][ln * SA + 0 + 8 * c];    \
                half8 a1 = *(const half8*)&sA0[RB][ln * SA + 32 + 8 * c];   \
                /* x(t+1) copy in the ds_read latency shadow */             \
                if ((T) < TT - 1 && xlane) {                                \
                    int tl1 = ((T) + 1) & 31;                               \
                    sA0[WB][xb * SA + 50 + xd] =                            \
                        (_Float16)sX[xb * SXR + tl1 * 8 + xd];              \
                }                                                           \
                f32x4 acc[4];                                               \
                _Pragma("unroll")                                           \
                for (int p = 0; p < 4; ++p) {                               \
                    acc[p] = MFMAH(a0, bfr[p][0], bias4[p]);                \
                    acc[p] = MFMAH(a1, bfr[p][1], acc[p]);                  \
                }                                                           \
                __builtin_amdgcn_s_setprio(0);                              \
                CELL_UPDATE(acc, sA0, WB)                                   \
            }                                                               \
        } else {                                                            \
            if ((T) > 0) {                                                  \
                __builtin_amdgcn_s_setprio(1);                              \
                half8 a0 = *(const half8*)&sA0[RB][ln * SA + 0 + 8 * c];    \
                half8 a1 = *(const half8*)&sA0[RB][ln * SA + 32 + 8 * c];   \
                half8 a2 = *(const half8*)&sA1[RB][ln * SA + 0 + 8 * c];    \
                half8 a3 = *(const half8*)&sA1[RB][ln * SA + 32 + 8 * c];   \
                f32x4 acc[4];                                               \
                _Pragma("unroll")                                           \
                for (int p = 0; p < 4; ++p) {                               \
                    acc[p] = MFMAH(a0, bfr[p][0], bias4[p]);                \
                    acc[p] = MFMAH(a1, bfr[p][1], acc[p]);                  \
                    acc[p] = MFMAH(a2, bfr[p][2], acc[p]);                  \
                    acc[p] = MFMAH(a3, bfr[p][3], acc[p]);                  \
                }                                                           \
                __builtin_amdgcn_s_setprio(0);                              \
                CELL_UPDATE(acc, sA1, WB)                                   \
            }                                                               \
        }                                                                   \
        __syncthreads();                                                    \
    }

// ---- x chunk roll (call sites guarantee (T)&31 == 31) ----
#define STAGE(T)                                                            \
    if ((T) < TT - 1) {                                                     \
        _Pragma("unroll")                                                   \
        for (int q = 0; q < 5; ++q) {                                       \
            int e = tid + q * BLK, b_ = e / 160, r_ = e - b_ * 160;         \
            int ts = r_ / 5, d_ = r_ - ts * 5;                              \
            sX[b_ * SXR + ts * 8 + d_] = xr[q];                             \
        }                                                                   \
        if ((T) + 33 < TT) {                                                \
            _Pragma("unroll")                                               \
            for (int q = 0; q < 5; ++q) {                                   \
                int e = tid + q * BLK, b_ = e / 160, r_ = e - b_ * 160;     \
                xr[q] = x[(size_t)(bb0 + b_) * 2560 +                       \
                          (size_t)((T) + 33) * 5 + r_];                     \
            }                                                               \
        }                                                                   \
        __syncthreads();                                                    \
    }

__global__ __launch_bounds__(512, 2) void lstm2_v7(
    const float* __restrict__ x,     // [4096][512][5]
    const float* __restrict__ Wih0,  // [200][5]
    const float* __restrict__ Whh0,  // [200][50]
    const float* __restrict__ bih0,  // [200]
    const float* __restrict__ bhh0,  // [200]
    const float* __restrict__ Wih1,  // [200][50]
    const float* __restrict__ Whh1,  // [200][50]
    const float* __restrict__ bih1,  // [200]
    const float* __restrict__ bhh1,  // [200]
    const float* __restrict__ Wlin,  // [1][50]
    const float* __restrict__ blin,  // [1]
    float* __restrict__ out)         // [4096]
{
    // A buffers, double-buffered. sA0 row: [h0 k=0..49 | x k=50..54 | pad]
    // sA1 row: [h1 k=0..49 | pad]. Pads zeroed once, never rewritten.
    __shared__ __align__(16) _Float16 sA0[2][16 * SA];
    __shared__ __align__(16) _Float16 sA1[2][16 * SA];
    __shared__ __align__(16) float sX[16 * SXR];

    const int tid = threadIdx.x;
    const int w = tid >> 6, l = tid & 63, c = l >> 4, ln = l & 15;
    const int grp = w >> 2, wl = w & 3;
    const int bb0 = blockIdx.x * NB;
    const int j = 16 * wl + ln;
    const bool jv = (j < 50);

    // x-copy lanes: 20 lanes on each L0 wave (SIMD-balanced), 80 total
    const bool xlane = (grp == 0) && (l < 20);
    const int xb = 4 * w + l / 5, xd = l % 5;

    for (int i = tid; i < 2 * 16 * SA; i += BLK) {
        (&sA0[0][0])[i] = (_Float16)0.f;
        (&sA1[0][0])[i] = (_Float16)0.f;
    }

    // ---- single-f16 B-frags (pre-scaled) + bias-as-C, for all 512 steps ----
    // k-slot convention (A and B identical): k = 32*s + 8*c + jj.
    // gate scale: p=0(i),1(f),3(o): -log2e ; p=2(g): -2log2e.
    half8 bfr[4][4];
    f32x4 bias4[4];
#pragma unroll
    for (int p = 0; p < 4; ++p) {
        const float gs = (p == 2) ? (-2.f * LOG2E) : (-LOG2E);
        const int g = p * 50 + j;
#pragma unroll
        for (int s = 0; s < 4; ++s) {
            half8 tb;
#pragma unroll
            for (int jj = 0; jj < 8; ++jj) {
                int k = 32 * s + 8 * c + jj;
                float v = 0.f;
                if (jv) {
                    if (grp == 0) {
                        if (k < 50)      v = Whh0[g * 50 + k];
                        else if (k < 55) v = Wih0[g * 5 + (k - 50)];
                    } else {
                        if (k < 50)                  v = Wih1[g * 50 + k];
                        else if (k >= 64 && k < 114) v = Whh1[g * 50 + (k - 64)];
                    }
                }
                tb[jj] = (_Float16)(v * gs);
            }
            bfr[p][s] = tb;
        }
        float bv = jv ? ((grp == 0) ? (bih0[g] + bhh0[g]) : (bih1[g] + bhh1[g])) : 0.f;
        bv *= gs;
        f32x4 b4; b4[0] = bv; b4[1] = bv; b4[2] = bv; b4[3] = bv;
        bias4[p] = b4;
    }

    float cst[4] = {0.f, 0.f, 0.f, 0.f};   // cell state: batches 4c+r, own j

    // ---- x chunk 0 -> sX; prefetch chunk 1 into xr ----
    float xr[5];
#pragma unroll
    for (int q = 0; q < 5; ++q) {
        int e = tid + q * BLK, b = e / 160, r = e - b * 160;
        xr[q] = x[(size_t)(bb0 + b) * 2560 + r];
    }
#pragma unroll
    for (int q = 0; q < 5; ++q) {
        int e = tid + q * BLK, b = e / 160, r = e - b * 160;
        int ts = r / 5, d = r - ts * 5;
        sX[b * SXR + ts * 8 + d] = xr[q];
    }
#pragma unroll
    for (int q = 0; q < 5; ++q) {
        int e = tid + q * BLK, b = e / 160, r = e - b * 160;
        xr[q] = x[(size_t)(bb0 + b) * 2560 + 160 + r];
    }
    __syncthreads();   // zero-init + sX visible

    if (tid < 80) {    // x(0) -> buf[1] (tick 0 reads rb=1)
        int b = tid / 5, d = tid - 5 * b;
        sA0[1][b * SA + 50 + d] = (_Float16)x[(size_t)(bb0 + b) * 2560 + d];
    }
    __syncthreads();

    // ---- main loop, 2x unrolled (compile-time rb/wb) ----
    for (int t = 0; t < TT; t += 2) {
        TICK(t, 1, 0)
        if ((t & 31) == 30) { STAGE(t + 1) }   // (t+1)&31 == 31
        TICK(t + 1, 0, 1)
    }
    TICK(TT, 1, 0)

    // ---- linear head on final h1(511) (tick 512 wrote buf[0]) ----
    if (tid < NB) {
        float s = blin[0];
#pragma unroll
        for (int jj = 0; jj < 50; ++jj)
            s += Wlin[jj] * (float)sA1[0][tid * SA + jj];
        out[bb0 + tid] = s;
    }
}

extern "C" void kernel_launch(void* const* d_in, const int* in_sizes, int n_in,
                              void* d_out, int out_size, void* d_ws, size_t ws_size,
                              hipStream_t stream) {
    (void)in_sizes; (void)n_in; (void)d_ws; (void)ws_size; (void)out_size;
    const float* x    = (const float*)d_in[0];
    const float* Wih0 = (const float*)d_in[1];
    const float* Whh0 = (const float*)d_in[2];
    const float* bih0 = (const float*)d_in[3];
    const float* bhh0 = (const float*)d_in[4];
    const float* Wih1 = (const float*)d_in[5];
    const float* Whh1 = (const float*)d_in[6];
    const float* bih1 = (const float*)d_in[7];
    const float* bhh1 = (const float*)d_in[8];
    const float* Wlin = (const float*)d_in[9];
    const float* blin = (const float*)d_in[10];

    lstm2_v7<<<dim3(256), dim3(512), 0, stream>>>(
        x, Wih0, Whh0, bih0, bhh0, Wih1, Whh1, bih1, bhh1, Wlin, blin,
        (float*)d_out);
}

// Round 10
// 351.991 us; speedup vs baseline: 1.0648x; 1.0648x over previous
//
#include <hip/hip_runtime.h>

// Fused 2-layer LSTM (H=50, D=5, T=512, B=4096) + linear head — v8.
// = v7 math (absmax 4.88e-4) + lag-2 L1 + triple-buffered sA0 + pre-read.
//   * L1 waves process step t-2 (was t-1). Their h0 operand is 2 barriers
//     old -> a0/a1 ds_reads issue in the PREVIOUS tick (right after the
//     s0/s1 MFMAs free the registers) and land fully hidden. Post-barrier
//     the L1 wave starts MFMAs immediately, covering the L0 wave's ds_read
//     stall on the same SIMD.
//   * sA0 triple-buffered (h0(t)+x(t+1) -> buf[t%3]); sA1 stays double.
//   * L1 h-store unguarded (sA1 pad cols are multiplied by zero B rows).
// grid=256 (1 block/CU), block=512 (8 waves), NB=16 batches/block.
// Waves 0-3: layer-0 step t; waves 4-7: layer-1 step t-2; ONE barrier/tick.
// 7-trans cell update (5 exp2 + 2 rcp), bias as MFMA C operand, 2x unroll.

#define NB 16
#define BLK 512
#define TT 512
#define LOG2E 1.44269504088896340736f
#define SA 72            // _Float16 per A row (K=64 pad, skewed stride)
#define SXR 264          // floats per batch row of x chunk

typedef _Float16 half8 __attribute__((ext_vector_type(8)));
typedef __attribute__((ext_vector_type(4))) float f32x4;

#define MFMAH(a, b, c) __builtin_amdgcn_mfma_f32_16x16x32_f16((a), (b), (c), 0, 0, 0)

__device__ __forceinline__ float fexp2(float x) { return __builtin_amdgcn_exp2f(x); }
__device__ __forceinline__ float frcp(float x)  { return __builtin_amdgcn_rcpf(x); }

// ---- 7-trans activation + cell + h-write for 4 batch rows ----
// c' = [c(1+eu)(1+ev) + (1-ev)(1+ew)] / [(1+eu)(1+ev)(1+ew)]
// h  = (1-ez)/((1+ey)(1+ez)), ez = exp2(min(-2log2e*c', 80))
#define CELL_UPDATE(ACCX, DST, GUARD)                                       \
    _Pragma("unroll")                                                       \
    for (int r = 0; r < 4; ++r) {                                           \
        float eu = fexp2(ACCX[0][r]);   /* i */                             \
        float ew = fexp2(ACCX[1][r]);   /* f */                             \
        float ev = fexp2(ACCX[2][r]);   /* g (2x scale) */                  \
        float ey = fexp2(ACCX[3][r]);   /* o */                             \
        float pu = 1.f + eu, pw = 1.f + ew, pv = 1.f + ev;                  \
        float P  = pu * pv;                                                 \
        float rD = frcp(P * pw);                                            \
        float N  = cst[r] * P + (2.f - pv) * pw;                            \
        float cn = N * rD;                                                  \
        cst[r] = cn;                                                        \
        float za = fminf(cn * (-2.f * LOG2E), 80.f);                        \
        float ez = fexp2(za);                                               \
        float pz = 1.f + ez, py = 1.f + ey;                                 \
        float rQ = frcp(py * pz);                                           \
        float h  = (2.f - pz) * rQ;                                         \
        if (GUARD) (DST)[(4 * c + r) * SA + j] = (_Float16)h;               \
    }

// ---- one pipeline tick; RB1/WB1 are literal 0/1 (sA1); r3/w3 runtime ----
#define TICK(T, RB1, WB1)                                                   \
    {                                                                       \
        if (grp == 0) {                                                     \
            if ((T) < TT) {                                                 \
                __builtin_amdgcn_s_setprio(1);                              \
                half8 a0 = *(const half8*)&sA0[r3][ln * SA + 0 + 8 * c];    \
                half8 a1 = *(const half8*)&sA0[r3][ln * SA + 32 + 8 * c];   \
                /* x(T+1) copy in the ds_read latency shadow */             \
                if ((T) < TT - 1 && xlane) {                                \
                    int tl1 = ((T) + 1) & 31;                               \
                    sA0[w3][xb * SA + 50 + xd] =                            \
                        (_Float16)sX[xb * SXR + tl1 * 8 + xd];              \
                }                                                           \
                f32x4 acc[4];                                               \
                _Pragma("unroll")                                           \
                for (int p = 0; p < 4; ++p) {                               \
                    acc[p] = MFMAH(a0, bfr[p][0], bias4[p]);                \
                    acc[p] = MFMAH(a1, bfr[p][1], acc[p]);                  \
                }                                                           \
                __builtin_amdgcn_s_setprio(0);                              \
                CELL_UPDATE(acc, &sA0[w3][0], jv)                           \
            }                                                               \
        } else {                                                            \
            if ((T) >= 2) {                                                 \
                __builtin_amdgcn_s_setprio(1);                              \
                half8 a2 = *(const half8*)&sA1[RB1][ln * SA + 0 + 8 * c];   \
                half8 a3 = *(const half8*)&sA1[RB1][ln * SA + 32 + 8 * c];  \
                f32x4 acc[4];                                               \
                _Pragma("unroll")                                           \
                for (int p = 0; p < 4; ++p)                                 \
                    acc[p] = MFMAH(l1a0, bfr[p][0], bias4[p]);              \
                _Pragma("unroll")                                           \
                for (int p = 0; p < 4; ++p)                                 \
                    acc[p] = MFMAH(l1a1, bfr[p][1], acc[p]);                \
                /* pre-read next tick's h0 operands (regs just freed;     */\
                /* buf[r3] is stable this tick — writers touch buf[w3])   */\
                l1a0 = *(const half8*)&sA0[r3][ln * SA + 0 + 8 * c];        \
                l1a1 = *(const half8*)&sA0[r3][ln * SA + 32 + 8 * c];       \
                _Pragma("unroll")                                           \
                for (int p = 0; p < 4; ++p) {                               \
                    acc[p] = MFMAH(a2, bfr[p][2], acc[p]);                  \
                    acc[p] = MFMAH(a3, bfr[p][3], acc[p]);                  \
                }                                                           \
                __builtin_amdgcn_s_setprio(0);                              \
                CELL_UPDATE(acc, &sA1[WB1][0], true)                        \
            } else if ((T) == 1) {                                          \
                l1a0 = *(const half8*)&sA0[r3][ln * SA + 0 + 8 * c];        \
                l1a1 = *(const half8*)&sA0[r3][ln * SA + 32 + 8 * c];       \
            }                                                               \
        }                                                                   \
        __syncthreads();                                                    \
        r3 = w3; w3 = (w3 == 2) ? 0 : (w3 + 1);                             \
    }

// ---- x chunk roll (call sites guarantee (T)&31 == 31) ----
#define STAGE(T)                                                            \
    if ((T) < TT - 1) {                                                     \
        _Pragma("unroll")                                                   \
        for (int q = 0; q < 5; ++q) {                                       \
            int e = tid + q * BLK, b_ = e / 160, r_ = e - b_ * 160;         \
            int ts = r_ / 5, d_ = r_ - ts * 5;                              \
            sX[b_ * SXR + ts * 8 + d_] = xr[q];                             \
        }                                                                   \
        if ((T) + 33 < TT) {                                                \
            _Pragma("unroll")                                               \
            for (int q = 0; q < 5; ++q) {                                   \
                int e = tid + q * BLK, b_ = e / 160, r_ = e - b_ * 160;     \
                xr[q] = x[(size_t)(bb0 + b_) * 2560 +                       \
                          (size_t)((T) + 33) * 5 + r_];                     \
            }                                                               \
        }                                                                   \
        __syncthreads();                                                    \
    }

__global__ __launch_bounds__(512, 2) void lstm2_v8(
    const float* __restrict__ x,     // [4096][512][5]
    const float* __restrict__ Wih0,  // [200][5]
    const float* __restrict__ Whh0,  // [200][50]
    const float* __restrict__ bih0,  // [200]
    const float* __restrict__ bhh0,  // [200]
    const float* __restrict__ Wih1,  // [200][50]
    const float* __restrict__ Whh1,  // [200][50]
    const float* __restrict__ bih1,  // [200]
    const float* __restrict__ bhh1,  // [200]
    const float* __restrict__ Wlin,  // [1][50]
    const float* __restrict__ blin,  // [1]
    float* __restrict__ out)         // [4096]
{
    // sA0: TRIPLE-buffered rows [h0 k=0..49 | x k=50..54 | pad].
    // h0(t) + x(t+1) -> buf[t%3]; L0/L1 read buf[(t-1)%3].
    // sA1: double-buffered [h1 k=0..49 | pad(+harmless lane spill)].
    __shared__ __align__(16) _Float16 sA0[3][16 * SA];
    __shared__ __align__(16) _Float16 sA1[2][16 * SA];
    __shared__ __align__(16) float sX[16 * SXR];

    const int tid = threadIdx.x;
    const int w = tid >> 6, l = tid & 63, c = l >> 4, ln = l & 15;
    const int grp = w >> 2, wl = w & 3;
    const int bb0 = blockIdx.x * NB;
    const int j = 16 * wl + ln;
    const bool jv = (j < 50);

    // x-copy lanes: 20 lanes on each L0 wave (SIMD-balanced), 80 total
    const bool xlane = (grp == 0) && (l < 20);
    const int xb = 4 * w + l / 5, xd = l % 5;

    for (int i = tid; i < 3 * 16 * SA; i += BLK) (&sA0[0][0])[i] = (_Float16)0.f;
    for (int i = tid; i < 2 * 16 * SA; i += BLK) (&sA1[0][0])[i] = (_Float16)0.f;

    // ---- single-f16 B-frags (pre-scaled) + bias-as-C, for all 512 steps ----
    // k-slot convention (A and B identical): k = 32*s + 8*c + jj.
    // gate scale: p=0(i),1(f),3(o): -log2e ; p=2(g): -2log2e.
    half8 bfr[4][4];
    f32x4 bias4[4];
#pragma unroll
    for (int p = 0; p < 4; ++p) {
        const float gs = (p == 2) ? (-2.f * LOG2E) : (-LOG2E);
        const int g = p * 50 + j;
#pragma unroll
        for (int s = 0; s < 4; ++s) {
            half8 tb;
#pragma unroll
            for (int jj = 0; jj < 8; ++jj) {
                int k = 32 * s + 8 * c + jj;
                float v = 0.f;
                if (jv) {
                    if (grp == 0) {
                        if (k < 50)      v = Whh0[g * 50 + k];
                        else if (k < 55) v = Wih0[g * 5 + (k - 50)];
                    } else {
                        if (k < 50)                  v = Wih1[g * 50 + k];
                        else if (k >= 64 && k < 114) v = Whh1[g * 50 + (k - 64)];
                    }
                }
                tb[jj] = (_Float16)(v * gs);
            }
            bfr[p][s] = tb;
        }
        float bv = jv ? ((grp == 0) ? (bih0[g] + bhh0[g]) : (bih1[g] + bhh1[g])) : 0.f;
        bv *= gs;
        f32x4 b4; b4[0] = bv; b4[1] = bv; b4[2] = bv; b4[3] = bv;
        bias4[p] = b4;
    }

    float cst[4] = {0.f, 0.f, 0.f, 0.f};   // cell state: batches 4c+r, own j
    half8 l1a0 = {}, l1a1 = {};            // L1 pre-read h0 operands
    int r3 = 2, w3 = 0;                    // sA0 read/write buffer indices

    // ---- x chunk 0 -> sX; prefetch chunk 1 into xr ----
    float xr[5];
#pragma unroll
    for (int q = 0; q < 5; ++q) {
        int e = tid + q * BLK, b = e / 160, r = e - b * 160;
        xr[q] = x[(size_t)(bb0 + b) * 2560 + r];
    }
#pragma unroll
    for (int q = 0; q < 5; ++q) {
        int e = tid + q * BLK, b = e / 160, r = e - b * 160;
        int ts = r / 5, d = r - ts * 5;
        sX[b * SXR + ts * 8 + d] = xr[q];
    }
#pragma unroll
    for (int q = 0; q < 5; ++q) {
        int e = tid + q * BLK, b = e / 160, r = e - b * 160;
        xr[q] = x[(size_t)(bb0 + b) * 2560 + 160 + r];
    }
    __syncthreads();   // zero-init + sX visible

    if (tid < 80) {    // x(0) -> buf[2] (tick 0 reads r3=2)
        int b = tid / 5, d = tid - 5 * b;
        sA0[2][b * SA + 50 + d] = (_Float16)x[(size_t)(bb0 + b) * 2560 + d];
    }
    __syncthreads();

    // ---- main loop: 514 ticks (L0: t=0..511; L1: step t-2 at t=2..513) ----
    for (int t = 0; t < TT + 2; t += 2) {
        TICK(t, 1, 0)
        if ((t & 31) == 30) { STAGE(t + 1) }   // (t+1)&31 == 31
        TICK(t + 1, 0, 1)
    }

    // ---- linear head on final h1(511) (tick 513 wrote sA1[1]) ----
    if (tid < NB) {
        float s = blin[0];
#pragma unroll
        for (int jj = 0; jj < 50; ++jj)
            s += Wlin[jj] * (float)sA1[1][tid * SA + jj];
        out[bb0 + tid] = s;
    }
}

extern "C" void kernel_launch(void* const* d_in, const int* in_sizes, int n_in,
                              void* d_out, int out_size, void* d_ws, size_t ws_size,
                              hipStream_t stream) {
    (void)in_sizes; (void)n_in; (void)d_ws; (void)ws_size; (void)out_size;
    const float* x    = (const float*)d_in[0];
    const float* Wih0 = (const float*)d_in[1];
    const float* Whh0 = (const float*)d_in[2];
    const float* bih0 = (const float*)d_in[3];
    const float* bhh0 = (const float*)d_in[4];
    const float* Wih1 = (const float*)d_in[5];
    const float* Whh1 = (const float*)d_in[6];
    const float* bih1 = (const float*)d_in[7];
    const float* bhh1 = (const float*)d_in[8];
    const float* Wlin = (const float*)d_in[9];
    const float* blin = (const float*)d_in[10];

    lstm2_v8<<<dim3(256), dim3(512), 0, stream>>>(
        x, Wih0, Whh0, bih0, bhh0, Wih1, Whh1, bih1, bhh1, Wlin, blin,
        (float*)d_out);
}

// Round 11
// 338.264 us; speedup vs baseline: 1.1080x; 1.0406x over previous
//
#include <hip/hip_runtime.h>

// Fused 2-layer LSTM (H=50, D=5, T=512, B=4096) + linear head — v9.
// = v8 (352 us) + issue-slot micro-grind:
//   * sA0 QUAD-buffered + 4x-unrolled loop -> ALL buffer indices are
//     compile-time literals (no r3/w3 rotation, LDS bases fold into
//     ds offset immediates). Race margin: buf written at t+3, read at t+1.
//   * fma-refactored cell update: P=fma(pu,ev,pu) etc, 14->11 VALU/cell.
//   * STAGE prefetch issued AFTER the stage barrier (v8 issued it before,
//     so the barrier's vmcnt(0) drain ate the whole HBM latency).
// grid=256 (1 block/CU), block=512 (8 waves), NB=16 batches/block.
// Waves 0-3: layer-0 step t; waves 4-7: layer-1 step t-2 with pre-read
// h0 operands; ONE barrier/tick; 7-trans cell (5 exp2 + 2 rcp).

#define NB 16
#define BLK 512
#define TT 512
#define LOG2E 1.44269504088896340736f
#define SA 72            // _Float16 per A row (K=64 pad, skewed stride)
#define SXR 264          // floats per batch row of x chunk

typedef _Float16 half8 __attribute__((ext_vector_type(8)));
typedef __attribute__((ext_vector_type(4))) float f32x4;

#define MFMAH(a, b, c) __builtin_amdgcn_mfma_f32_16x16x32_f16((a), (b), (c), 0, 0, 0)

__device__ __forceinline__ float fexp2(float x) { return __builtin_amdgcn_exp2f(x); }
__device__ __forceinline__ float frcp(float x)  { return __builtin_amdgcn_rcpf(x); }

// ---- 7-trans, fma-packed cell update + h-write for 4 batch rows ----
// c' = [c·P + (1-ev)(1+ew)] / [P(1+ew)],  P = (1+eu)(1+ev)
// h  = (1-ez)/((1+ey)(1+ez)),  ez = exp2(min(-2log2e·c', 80))
#define CELL_UPDATE(ACCX, DST, GUARD)                                       \
    _Pragma("unroll")                                                       \
    for (int r = 0; r < 4; ++r) {                                           \
        float eu = fexp2(ACCX[0][r]);   /* i */                             \
        float ew = fexp2(ACCX[1][r]);   /* f */                             \
        float ev = fexp2(ACCX[2][r]);   /* g (2x scale) */                  \
        float ey = fexp2(ACCX[3][r]);   /* o */                             \
        float pu = 1.f + eu;                                                \
        float P  = __builtin_fmaf(pu, ev, pu);                              \
        float PD = __builtin_fmaf(P, ew, P);                                \
        float s_ = 1.f - ev;                                                \
        float t2 = __builtin_fmaf(s_, ew, s_);                              \
        float N  = __builtin_fmaf(cst[r], P, t2);                           \
        float rD = frcp(PD);                                                \
        float cn = N * rD;                                                  \
        cst[r] = cn;                                                        \
        float za = fminf(cn * (-2.f * LOG2E), 80.f);                        \
        float ez = fexp2(za);                                               \
        float py = 1.f + ey;                                                \
        float Q  = __builtin_fmaf(py, ez, py);                              \
        float rQ = frcp(Q);                                                 \
        float g2 = 1.f - ez;                                                \
        float h  = g2 * rQ;                                                 \
        if (GUARD) (DST)[(4 * c + r) * SA + j] = (_Float16)h;               \
    }

// ---- one pipeline tick; RB1/WB1 (sA1) and R4/W4 (sA0) are literals ----
#define TICK(T, RB1, WB1, R4, W4)                                           \
    {                                                                       \
        if (grp == 0) {                                                     \
            if ((T) < TT) {                                                 \
                __builtin_amdgcn_s_setprio(1);                              \
                half8 a0 = *(const half8*)&sA0[R4][ln * SA + 0 + 8 * c];    \
                half8 a1 = *(const half8*)&sA0[R4][ln * SA + 32 + 8 * c];   \
                /* x(T+1) copy in the ds_read latency shadow */             \
                if ((T) < TT - 1 && xlane) {                                \
                    int tl1 = ((T) + 1) & 31;                               \
                    sA0[W4][xb * SA + 50 + xd] =                            \
                        (_Float16)sX[xb * SXR + tl1 * 8 + xd];              \
                }                                                           \
                f32x4 acc[4];                                               \
                _Pragma("unroll")                                           \
                for (int p = 0; p < 4; ++p) {                               \
                    acc[p] = MFMAH(a0, bfr[p][0], bias4[p]);                \
                    acc[p] = MFMAH(a1, bfr[p][1], acc[p]);                  \
                }                                                           \
                __builtin_amdgcn_s_setprio(0);                              \
                CELL_UPDATE(acc, &sA0[W4][0], jv)                           \
            }                                                               \
        } else {                                                            \
            if ((T) >= 2) {                                                 \
                __builtin_amdgcn_s_setprio(1);                              \
                half8 a2 = *(const half8*)&sA1[RB1][ln * SA + 0 + 8 * c];   \
                half8 a3 = *(const half8*)&sA1[RB1][ln * SA + 32 + 8 * c];  \
                f32x4 acc[4];                                               \
                _Pragma("unroll")                                           \
                for (int p = 0; p < 4; ++p)                                 \
                    acc[p] = MFMAH(l1a0, bfr[p][0], bias4[p]);              \
                _Pragma("unroll")                                           \
                for (int p = 0; p < 4; ++p)                                 \
                    acc[p] = MFMAH(l1a1, bfr[p][1], acc[p]);                \
                /* pre-read next tick's h0 operands (regs just freed;     */\
                /* buf[R4] is stable this tick — writers touch buf[W4])   */\
                l1a0 = *(const half8*)&sA0[R4][ln * SA + 0 + 8 * c];        \
                l1a1 = *(const half8*)&sA0[R4][ln * SA + 32 + 8 * c];       \
                _Pragma("unroll")                                           \
                for (int p = 0; p < 4; ++p) {                               \
                    acc[p] = MFMAH(a2, bfr[p][2], acc[p]);                  \
                    acc[p] = MFMAH(a3, bfr[p][3], acc[p]);                  \
                }                                                           \
                __builtin_amdgcn_s_setprio(0);                              \
                CELL_UPDATE(acc, &sA1[WB1][0], true)                        \
            } else if ((T) == 1) {                                          \
                l1a0 = *(const half8*)&sA0[R4][ln * SA + 0 + 8 * c];        \
                l1a1 = *(const half8*)&sA0[R4][ln * SA + 32 + 8 * c];       \
            }                                                               \
        }                                                                   \
        __syncthreads();                                                    \
    }

// ---- x chunk roll (call sites guarantee (T)&31 == 31) ----
// prefetch issued AFTER the barrier: next vmcnt(0) drain is a full tick away
#define STAGE(T)                                                            \
    if ((T) < TT - 1) {                                                     \
        _Pragma("unroll")                                                   \
        for (int q = 0; q < 5; ++q) {                                       \
            int e = tid + q * BLK, b_ = e / 160, r_ = e - b_ * 160;         \
            int ts = r_ / 5, d_ = r_ - ts * 5;                              \
            sX[b_ * SXR + ts * 8 + d_] = xr[q];                             \
        }                                                                   \
        __syncthreads();                                                    \
        if ((T) + 33 < TT) {                                                \
            _Pragma("unroll")                                               \
            for (int q = 0; q < 5; ++q) {                                   \
                int e = tid + q * BLK, b_ = e / 160, r_ = e - b_ * 160;     \
                xr[q] = x[(size_t)(bb0 + b_) * 2560 +                       \
                          (size_t)((T) + 33) * 5 + r_];                     \
            }                                                               \
        }                                                                   \
    }

__global__ __launch_bounds__(512, 2) void lstm2_v9(
    const float* __restrict__ x,     // [4096][512][5]
    const float* __restrict__ Wih0,  // [200][5]
    const float* __restrict__ Whh0,  // [200][50]
    const float* __restrict__ bih0,  // [200]
    const float* __restrict__ bhh0,  // [200]
    const float* __restrict__ Wih1,  // [200][50]
    const float* __restrict__ Whh1,  // [200][50]
    const float* __restrict__ bih1,  // [200]
    const float* __restrict__ bhh1,  // [200]
    const float* __restrict__ Wlin,  // [1][50]
    const float* __restrict__ blin,  // [1]
    float* __restrict__ out)         // [4096]
{
    // sA0: QUAD-buffered rows [h0 k=0..49 | x k=50..54 | pad].
    // h0(t)+x(t+1) -> buf[t&3]; readers use buf[(t-1)&3].
    // sA1: double-buffered [h1 k=0..49 | pad(+harmless lane spill)].
    __shared__ __align__(16) _Float16 sA0[4][16 * SA];
    __shared__ __align__(16) _Float16 sA1[2][16 * SA];
    __shared__ __align__(16) float sX[16 * SXR];

    const int tid = threadIdx.x;
    const int w = tid >> 6, l = tid & 63, c = l >> 4, ln = l & 15;
    const int grp = w >> 2, wl = w & 3;
    const int bb0 = blockIdx.x * NB;
    const int j = 16 * wl + ln;
    const bool jv = (j < 50);

    // x-copy lanes: 20 lanes on each L0 wave (SIMD-balanced), 80 total
    const bool xlane = (grp == 0) && (l < 20);
    const int xb = 4 * w + l / 5, xd = l % 5;

    for (int i = tid; i < 4 * 16 * SA; i += BLK) (&sA0[0][0])[i] = (_Float16)0.f;
    for (int i = tid; i < 2 * 16 * SA; i += BLK) (&sA1[0][0])[i] = (_Float16)0.f;

    // ---- single-f16 B-frags (pre-scaled) + bias-as-C, for all 512 steps ----
    // k-slot convention (A and B identical): k = 32*s + 8*c + jj.
    // gate scale: p=0(i),1(f),3(o): -log2e ; p=2(g): -2log2e.
    half8 bfr[4][4];
    f32x4 bias4[4];
#pragma unroll
    for (int p = 0; p < 4; ++p) {
        const float gs = (p == 2) ? (-2.f * LOG2E) : (-LOG2E);
        const int g = p * 50 + j;
#pragma unroll
        for (int s = 0; s < 4; ++s) {
            half8 tb;
#pragma unroll
            for (int jj = 0; jj < 8; ++jj) {
                int k = 32 * s + 8 * c + jj;
                float v = 0.f;
                if (jv) {
                    if (grp == 0) {
                        if (k < 50)      v = Whh0[g * 50 + k];
                        else if (k < 55) v = Wih0[g * 5 + (k - 50)];
                    } else {
                        if (k < 50)                  v = Wih1[g * 50 + k];
                        else if (k >= 64 && k < 114) v = Whh1[g * 50 + (k - 64)];
                    }
                }
                tb[jj] = (_Float16)(v * gs);
            }
            bfr[p][s] = tb;
        }
        float bv = jv ? ((grp == 0) ? (bih0[g] + bhh0[g]) : (bih1[g] + bhh1[g])) : 0.f;
        bv *= gs;
        f32x4 b4; b4[0] = bv; b4[1] = bv; b4[2] = bv; b4[3] = bv;
        bias4[p] = b4;
    }

    float cst[4] = {0.f, 0.f, 0.f, 0.f};   // cell state: batches 4c+r, own j
    half8 l1a0 = {}, l1a1 = {};            // L1 pre-read h0 operands

    // ---- x chunk 0 -> sX; prefetch chunk 1 into xr ----
    float xr[5];
#pragma unroll
    for (int q = 0; q < 5; ++q) {
        int e = tid + q * BLK, b = e / 160, r = e - b * 160;
        xr[q] = x[(size_t)(bb0 + b) * 2560 + r];
    }
#pragma unroll
    for (int q = 0; q < 5; ++q) {
        int e = tid + q * BLK, b = e / 160, r = e - b * 160;
        int ts = r / 5, d = r - ts * 5;
        sX[b * SXR + ts * 8 + d] = xr[q];
    }
#pragma unroll
    for (int q = 0; q < 5; ++q) {
        int e = tid + q * BLK, b = e / 160, r = e - b * 160;
        xr[q] = x[(size_t)(bb0 + b) * 2560 + 160 + r];
    }
    __syncthreads();   // zero-init + sX visible

    if (tid < 80) {    // x(0) -> buf[3] (tick 0 reads R4=3)
        int b = tid / 5, d = tid - 5 * b;
        sA0[3][b * SA + 50 + d] = (_Float16)x[(size_t)(bb0 + b) * 2560 + d];
    }
    __syncthreads();

    // ---- main loop: 4x unrolled, all buffer indices literal ----
    // tick T: sA0 reads buf[(T-1)&3], writes buf[T&3]; sA1 RB=(T+1)&1, WB=T&1.
    for (int t = 0; t < TT; t += 4) {
        TICK(t + 0, 1, 0, 3, 0)
        TICK(t + 1, 0, 1, 0, 1)
        TICK(t + 2, 1, 0, 1, 2)
        if ((t & 31) == 28) { STAGE(t + 3) }   // (t+3)&31 == 31
        TICK(t + 3, 0, 1, 2, 3)
    }
    TICK(TT,     1, 0, 3, 0)   // L1 step 510
    TICK(TT + 1, 0, 1, 0, 1)   // L1 step 511 -> sA1[1]

    // ---- linear head on final h1(511) (tick 513 wrote sA1[1]) ----
    if (tid < NB) {
        float s = blin[0];
#pragma unroll
        for (int jj = 0; jj < 50; ++jj)
            s += Wlin[jj] * (float)sA1[1][tid * SA + jj];
        out[bb0 + tid] = s;
    }
}

extern "C" void kernel_launch(void* const* d_in, const int* in_sizes, int n_in,
                              void* d_out, int out_size, void* d_ws, size_t ws_size,
                              hipStream_t stream) {
    (void)in_sizes; (void)n_in; (void)d_ws; (void)ws_size; (void)out_size;
    const float* x    = (const float*)d_in[0];
    const float* Wih0 = (const float*)d_in[1];
    const float* Whh0 = (const float*)d_in[2];
    const float* bih0 = (const float*)d_in[3];
    const float* bhh0 = (const float*)d_in[4];
    const float* Wih1 = (const float*)d_in[5];
    const float* Whh1 = (const float*)d_in[6];
    const float* bih1 = (const float*)d_in[7];
    const float* bhh1 = (const float*)d_in[8];
    const float* Wlin = (const float*)d_in[9];
    const float* blin = (const float*)d_in[10];

    lstm2_v9<<<dim3(256), dim3(512), 0, stream>>>(
        x, Wih0, Whh0, bih0, bhh0, Wih1, Whh1, bih1, bhh1, Wlin, blin,
        (float*)d_out);
}

// Round 12
// 329.493 us; speedup vs baseline: 1.1375x; 1.0266x over previous
//
#include <hip/hip_runtime.h>

// Fused 2-layer LSTM (H=50, D=5, T=512, B=4096) + linear head — v10.
// = v9 (338 us) + final micro-grind (math bit-identical):
//   * phase-burst cell update: 16 gate exp2s -> algebra -> 4 za exp2s ->
//     Q/rcp/h. Groups trans so the SIMD-mate wave interleaves VALU/MFMA.
//   * hoisted LDS addressing: aoff/hoff bases in registers, r*SA and
//     buffer bases fold to ds offset literals; running xidx counter.
// grid=256 (1 block/CU), block=512 (8 waves), NB=16 batches/block.
// Waves 0-3: layer-0 step t; waves 4-7: layer-1 step t-2 (pre-read h0);
// ONE barrier/tick; quad-buffered sA0, 4x unroll, literal buffer indices;
// 7-trans cell (5 exp2 + 2 rcp — proven minimal); bias as MFMA C operand.

#define NB 16
#define BLK 512
#define TT 512
#define LOG2E 1.44269504088896340736f
#define SA 72            // _Float16 per A row (K=64 pad, skewed stride)
#define SXR 264          // floats per batch row of x chunk

typedef _Float16 half8 __attribute__((ext_vector_type(8)));
typedef __attribute__((ext_vector_type(4))) float f32x4;

#define MFMAH(a, b, c) __builtin_amdgcn_mfma_f32_16x16x32_f16((a), (b), (c), 0, 0, 0)

__device__ __forceinline__ float fexp2(float x) { return __builtin_amdgcn_exp2f(x); }
__device__ __forceinline__ float frcp(float x)  { return __builtin_amdgcn_rcpf(x); }

// ---- phase-burst cell update + h-write for 4 batch rows ----
// c' = [c·P + (1-ev)(1+ew)] / [P(1+ew)],  P = (1+eu)(1+ev)
// h  = (1-ez)/((1+ey)(1+ez)),  ez = exp2(min(-2log2e·c', 80))
#define CELL_UPDATE(ACCX, DSTB, GUARD)                                      \
    {                                                                       \
        float eu[4], ew[4], ev[4], ey[4];                                   \
        _Pragma("unroll")                                                   \
        for (int r = 0; r < 4; ++r) {                                       \
            eu[r] = fexp2(ACCX[0][r]);                                      \
            ew[r] = fexp2(ACCX[1][r]);                                      \
            ev[r] = fexp2(ACCX[2][r]);                                      \
            ey[r] = fexp2(ACCX[3][r]);                                      \
        }                                                                   \
        float cn[4];                                                        \
        _Pragma("unroll")                                                   \
        for (int r = 0; r < 4; ++r) {                                       \
            float pu = 1.f + eu[r];                                         \
            float P  = __builtin_fmaf(pu, ev[r], pu);                       \
            float PD = __builtin_fmaf(P, ew[r], P);                         \
            float s_ = 1.f - ev[r];                                         \
            float t2 = __builtin_fmaf(s_, ew[r], s_);                       \
            float N  = __builtin_fmaf(cst[r], P, t2);                       \
            cn[r] = N * frcp(PD);                                           \
            cst[r] = cn[r];                                                 \
        }                                                                   \
        float ez[4];                                                        \
        _Pragma("unroll")                                                   \
        for (int r = 0; r < 4; ++r)                                         \
            ez[r] = fexp2(fminf(cn[r] * (-2.f * LOG2E), 80.f));             \
        _Pragma("unroll")                                                   \
        for (int r = 0; r < 4; ++r) {                                       \
            float py = 1.f + ey[r];                                         \
            float Q  = __builtin_fmaf(py, ez[r], py);                       \
            float h  = (1.f - ez[r]) * frcp(Q);                             \
            if (GUARD) (DSTB)[hoff + r * SA] = (_Float16)h;                 \
        }                                                                   \
    }

// ---- one pipeline tick; RB1/WB1 (sA1) and R4/W4 (sA0) are literals ----
#define TICK(T, RB1, WB1, R4, W4)                                           \
    {                                                                       \
        if (grp == 0) {                                                     \
            if ((T) < TT) {                                                 \
                __builtin_amdgcn_s_setprio(1);                              \
                half8 a0 = *(const half8*)(&sA0[R4][0] + aoff0);            \
                half8 a1 = *(const half8*)(&sA0[R4][0] + aoff1);            \
                /* x(T+1) copy in the ds_read latency shadow */             \
                if ((T) < TT - 1 && xlane) {                                \
                    sA0[W4][xdst] = (_Float16)sXp[xidx];                    \
                    xidx = (xidx + 8) & 255;                                \
                }                                                           \
                f32x4 acc[4];                                               \
                _Pragma("unroll")                                           \
                for (int p = 0; p < 4; ++p) {                               \
                    acc[p] = MFMAH(a0, bfr[p][0], bias4[p]);                \
                    acc[p] = MFMAH(a1, bfr[p][1], acc[p]);                  \
                }                                                           \
                __builtin_amdgcn_s_setprio(0);                              \
                CELL_UPDATE(acc, &sA0[W4][0], jv)                           \
            }                                                               \
        } else {                                                            \
            if ((T) >= 2) {                                                 \
                __builtin_amdgcn_s_setprio(1);                              \
                half8 a2 = *(const half8*)(&sA1[RB1][0] + aoff0);           \
                half8 a3 = *(const half8*)(&sA1[RB1][0] + aoff1);           \
                f32x4 acc[4];                                               \
                _Pragma("unroll")                                           \
                for (int p = 0; p < 4; ++p)                                 \
                    acc[p] = MFMAH(l1a0, bfr[p][0], bias4[p]);              \
                _Pragma("unroll")                                           \
                for (int p = 0; p < 4; ++p)                                 \
                    acc[p] = MFMAH(l1a1, bfr[p][1], acc[p]);                \
                /* pre-read next tick's h0 operands (regs just freed;     */\
                /* buf[R4] is stable this tick — writers touch buf[W4])   */\
                l1a0 = *(const half8*)(&sA0[R4][0] + aoff0);                \
                l1a1 = *(const half8*)(&sA0[R4][0] + aoff1);                \
                _Pragma("unroll")                                           \
                for (int p = 0; p < 4; ++p) {                               \
                    acc[p] = MFMAH(a2, bfr[p][2], acc[p]);                  \
                    acc[p] = MFMAH(a3, bfr[p][3], acc[p]);                  \
                }                                                           \
                __builtin_amdgcn_s_setprio(0);                              \
                CELL_UPDATE(acc, &sA1[WB1][0], true)                        \
            } else if ((T) == 1) {                                          \
                l1a0 = *(const half8*)(&sA0[R4][0] + aoff0);                \
                l1a1 = *(const half8*)(&sA0[R4][0] + aoff1);                \
            }                                                               \
        }                                                                   \
        __syncthreads();                                                    \
    }

// ---- x chunk roll (call sites guarantee (T)&31 == 31) ----
// prefetch issued AFTER the barrier: next vmcnt(0) drain is a full tick away
#define STAGE(T)                                                            \
    if ((T) < TT - 1) {                                                     \
        _Pragma("unroll")                                                   \
        for (int q = 0; q < 5; ++q) {                                       \
            int e = tid + q * BLK, b_ = e / 160, r_ = e - b_ * 160;         \
            int ts = r_ / 5, d_ = r_ - ts * 5;                              \
            sX[b_ * SXR + ts * 8 + d_] = xr[q];                             \
        }                                                                   \
        __syncthreads();                                                    \
        if ((T) + 33 < TT) {                                                \
            _Pragma("unroll")                                               \
            for (int q = 0; q < 5; ++q) {                                   \
                int e = tid + q * BLK, b_ = e / 160, r_ = e - b_ * 160;     \
                xr[q] = x[(size_t)(bb0 + b_) * 2560 +                       \
                          (size_t)((T) + 33) * 5 + r_];                     \
            }                                                               \
        }                                                                   \
    }

__global__ __launch_bounds__(512, 2) void lstm2_v10(
    const float* __restrict__ x,     // [4096][512][5]
    const float* __restrict__ Wih0,  // [200][5]
    const float* __restrict__ Whh0,  // [200][50]
    const float* __restrict__ bih0,  // [200]
    const float* __restrict__ bhh0,  // [200]
    const float* __restrict__ Wih1,  // [200][50]
    const float* __restrict__ Whh1,  // [200][50]
    const float* __restrict__ bih1,  // [200]
    const float* __restrict__ bhh1,  // [200]
    const float* __restrict__ Wlin,  // [1][50]
    const float* __restrict__ blin,  // [1]
    float* __restrict__ out)         // [4096]
{
    // sA0: QUAD-buffered rows [h0 k=0..49 | x k=50..54 | pad].
    // h0(t)+x(t+1) -> buf[t&3]; readers use buf[(t-1)&3].
    // sA1: double-buffered [h1 k=0..49 | pad(+harmless lane spill)].
    __shared__ __align__(16) _Float16 sA0[4][16 * SA];
    __shared__ __align__(16) _Float16 sA1[2][16 * SA];
    __shared__ __align__(16) float sX[16 * SXR];

    const int tid = threadIdx.x;
    const int w = tid >> 6, l = tid & 63, c = l >> 4, ln = l & 15;
    const int grp = w >> 2, wl = w & 3;
    const int bb0 = blockIdx.x * NB;
    const int j = 16 * wl + ln;
    const bool jv = (j < 50);

    // hoisted LDS addressing (all loop-invariant)
    const int aoff0 = ln * SA + 8 * c;        // A-frag base, s-slot 0
    const int aoff1 = ln * SA + 32 + 8 * c;   // A-frag base, s-slot 1
    const int hoff  = (4 * c) * SA + j;       // h-store base (+ r*SA literal)

    // x-copy lanes: 20 lanes on each L0 wave (SIMD-balanced), 80 total
    const bool xlane = (grp == 0) && (l < 20);
    const int xb = 4 * w + l / 5, xd = l % 5;
    const int xdst = xb * SA + 50 + xd;       // sA0 x-slot (buffer via literal)
    const float* sXp = &sX[xb * SXR + xd];    // sX base; + running xidx
    int xidx = 8;                             // tick 0 copies x(1) -> slot 1*8

    for (int i = tid; i < 4 * 16 * SA; i += BLK) (&sA0[0][0])[i] = (_Float16)0.f;
    for (int i = tid; i < 2 * 16 * SA; i += BLK) (&sA1[0][0])[i] = (_Float16)0.f;

    // ---- single-f16 B-frags (pre-scaled) + bias-as-C, for all 512 steps ----
    // k-slot convention (A and B identical): k = 32*s + 8*c + jj.
    // gate scale: p=0(i),1(f),3(o): -log2e ; p=2(g): -2log2e.
    half8 bfr[4][4];
    f32x4 bias4[4];
#pragma unroll
    for (int p = 0; p < 4; ++p) {
        const float gs = (p == 2) ? (-2.f * LOG2E) : (-LOG2E);
        const int g = p * 50 + j;
#pragma unroll
        for (int s = 0; s < 4; ++s) {
            half8 tb;
#pragma unroll
            for (int jj = 0; jj < 8; ++jj) {
                int k = 32 * s + 8 * c + jj;
                float v = 0.f;
                if (jv) {
                    if (grp == 0) {
                        if (k < 50)      v = Whh0[g * 50 + k];
                        else if (k < 55) v = Wih0[g * 5 + (k - 50)];
                    } else {
                        if (k < 50)                  v = Wih1[g * 50 + k];
                        else if (k >= 64 && k < 114) v = Whh1[g * 50 + (k - 64)];
                    }
                }
                tb[jj] = (_Float16)(v * gs);
            }
            bfr[p][s] = tb;
        }
        float bv = jv ? ((grp == 0) ? (bih0[g] + bhh0[g]) : (bih1[g] + bhh1[g])) : 0.f;
        bv *= gs;
        f32x4 b4; b4[0] = bv; b4[1] = bv; b4[2] = bv; b4[3] = bv;
        bias4[p] = b4;
    }

    float cst[4] = {0.f, 0.f, 0.f, 0.f};   // cell state: batches 4c+r, own j
    half8 l1a0 = {}, l1a1 = {};            // L1 pre-read h0 operands

    // ---- x chunk 0 -> sX; prefetch chunk 1 into xr ----
    float xr[5];
#pragma unroll
    for (int q = 0; q < 5; ++q) {
        int e = tid + q * BLK, b = e / 160, r = e - b * 160;
        xr[q] = x[(size_t)(bb0 + b) * 2560 + r];
    }
#pragma unroll
    for (int q = 0; q < 5; ++q) {
        int e = tid + q * BLK, b = e / 160, r = e - b * 160;
        int ts = r / 5, d = r - ts * 5;
        sX[b * SXR + ts * 8 + d] = xr[q];
    }
#pragma unroll
    for (int q = 0; q < 5; ++q) {
        int e = tid + q * BLK, b = e / 160, r = e - b * 160;
        xr[q] = x[(size_t)(bb0 + b) * 2560 + 160 + r];
    }
    __syncthreads();   // zero-init + sX visible

    if (tid < 80) {    // x(0) -> buf[3] (tick 0 reads R4=3)
        int b = tid / 5, d = tid - 5 * b;
        sA0[3][b * SA + 50 + d] = (_Float16)x[(size_t)(bb0 + b) * 2560 + d];
    }
    __syncthreads();

    // ---- main loop: 4x unrolled, all buffer indices literal ----
    // tick T: sA0 reads buf[(T-1)&3], writes buf[T&3]; sA1 RB=(T+1)&1, WB=T&1.
    for (int t = 0; t < TT; t += 4) {
        TICK(t + 0, 1, 0, 3, 0)
        TICK(t + 1, 0, 1, 0, 1)
        TICK(t + 2, 1, 0, 1, 2)
        if ((t & 31) == 28) { STAGE(t + 3) }   // (t+3)&31 == 31
        TICK(t + 3, 0, 1, 2, 3)
    }
    TICK(TT,     1, 0, 3, 0)   // L1 step 510
    TICK(TT + 1, 0, 1, 0, 1)   // L1 step 511 -> sA1[1]

    // ---- linear head on final h1(511) (tick 513 wrote sA1[1]) ----
    if (tid < NB) {
        float s = blin[0];
#pragma unroll
        for (int jj = 0; jj < 50; ++jj)
            s += Wlin[jj] * (float)sA1[1][tid * SA + jj];
        out[bb0 + tid] = s;
    }
}

extern "C" void kernel_launch(void* const* d_in, const int* in_sizes, int n_in,
                              void* d_out, int out_size, void* d_ws, size_t ws_size,
                              hipStream_t stream) {
    (void)in_sizes; (void)n_in; (void)d_ws; (void)ws_size; (void)out_size;
    const float* x    = (const float*)d_in[0];
    const float* Wih0 = (const float*)d_in[1];
    const float* Whh0 = (const float*)d_in[2];
    const float* bih0 = (const float*)d_in[3];
    const float* bhh0 = (const float*)d_in[4];
    const float* Wih1 = (const float*)d_in[5];
    const float* Whh1 = (const float*)d_in[6];
    const float* bih1 = (const float*)d_in[7];
    const float* bhh1 = (const float*)d_in[8];
    const float* Wlin = (const float*)d_in[9];
    const float* blin = (const float*)d_in[10];

    lstm2_v10<<<dim3(256), dim3(512), 0, stream>>>(
        x, Wih0, Whh0, bih0, bhh0, Wih1, Whh1, bih1, bhh1, Wlin, blin,
        (float*)d_out);
}